// Round 3
// baseline (4833.725 us; speedup 1.0000x reference)
//
#include <hip/hip_runtime.h>

namespace {

constexpr int kNU = 100000;
constexpr int kNI = 50000;
constexpr int kN  = 150000;
constexpr int kH  = 128;
constexpr int kEP = 2000000;
constexpr int kEN = 1000000;
constexpr int kL  = 2;

constexpr int SCAN_BS = 256;
constexpr int SCAN_IT = 4;
constexpr int SCAN_TILE = SCAN_BS * SCAN_IT;

// force a wave-uniform pointer into SGPRs so A-loads select SMEM (s_load)
__device__ inline const float* uptr(const float* p) {
  uint64_t v = (uint64_t)(uintptr_t)p;
  uint32_t lo = __builtin_amdgcn_readfirstlane((uint32_t)(v & 0xffffffffull));
  uint32_t hi = __builtin_amdgcn_readfirstlane((uint32_t)(v >> 32));
  return (const float*)(uintptr_t)(((uint64_t)hi << 32) | lo);
}

// ---- degree counting ----
__global__ void count_kernel(const int* __restrict__ dst, int E, int* __restrict__ deg) {
  int t = blockIdx.x * blockDim.x + threadIdx.x;
  if (t < E) atomicAdd(&deg[dst[t]], 1);
}

__global__ void inv_kernel(const int* __restrict__ deg, float* __restrict__ inv, int n) {
  int t = blockIdx.x * blockDim.x + threadIdx.x;
  if (t < n) inv[t] = 1.0f / fmaxf((float)deg[t], 1.0f);
}

// ---- 3-phase exclusive scan ----
__global__ void scan_partial(const int* __restrict__ deg, int n,
                             int* __restrict__ off, int* __restrict__ sums) {
  __shared__ int sh[SCAN_BS];
  const int t = threadIdx.x;
  const int base = blockIdx.x * SCAN_TILE;
  int v[SCAN_IT];
  int run = 0;
#pragma unroll
  for (int j = 0; j < SCAN_IT; ++j) {
    int idx = base + t * SCAN_IT + j;
    v[j] = (idx < n) ? deg[idx] : 0;
    run += v[j];
  }
  sh[t] = run;
  __syncthreads();
  for (int d = 1; d < SCAN_BS; d <<= 1) {
    int x = (t >= d) ? sh[t - d] : 0;
    __syncthreads();
    sh[t] += x;
    __syncthreads();
  }
  int acc = sh[t] - run;
  if (t == SCAN_BS - 1) sums[blockIdx.x] = sh[t];
#pragma unroll
  for (int j = 0; j < SCAN_IT; ++j) {
    int idx = base + t * SCAN_IT + j;
    acc += v[j];
    if (idx < n) off[idx + 1] = acc;
  }
}

__global__ void scan_sums(int* __restrict__ sums, int nb) {
  __shared__ int sh[SCAN_BS];
  const int t = threadIdx.x;
  int v = (t < nb) ? sums[t] : 0;
  sh[t] = v;
  __syncthreads();
  for (int d = 1; d < SCAN_BS; d <<= 1) {
    int x = (t >= d) ? sh[t - d] : 0;
    __syncthreads();
    sh[t] += x;
    __syncthreads();
  }
  if (t < nb) sums[t] = sh[t] - v;
}

__global__ void scan_add(int* __restrict__ off, int n, const int* __restrict__ sums) {
  int t = blockIdx.x * blockDim.x + threadIdx.x;
  if (t == 0) off[0] = 0;
  if (t < n) off[t + 1] += sums[t / SCAN_TILE];
}

// ---- CSR fill ----
__global__ void fill_kernel(const int* __restrict__ src, const int* __restrict__ dst, int E,
                            int* __restrict__ cursor, int* __restrict__ eids) {
  int t = blockIdx.x * blockDim.x + threadIdx.x;
  if (t < E) {
    int p = atomicAdd(&cursor[dst[t]], 1);
    eids[p] = src[t];
  }
}

// ---- CSR gather-mean (full 128-wide) ----
template <bool SPLIT>
__global__ __launch_bounds__(256) void agg_csr(
    const int* __restrict__ off, const int* __restrict__ eids,
    const float* __restrict__ inv,
    const float* __restrict__ zu, const float* __restrict__ zi,
    float* __restrict__ aggOut) {
  const int g = threadIdx.x >> 5;
  const int lane = threadIdx.x & 31;
  const int row = blockIdx.x * 8 + g;
  if (row >= kN) return;
  const int s = off[row], e = off[row + 1];
  float4 acc = make_float4(0.f, 0.f, 0.f, 0.f);
  int i = s;
  for (; i + 2 <= e; i += 2) {
    int s0 = eids[i], s1 = eids[i + 1];
    const float* r0;
    const float* r1;
    if (SPLIT) {
      r0 = (s0 < kNU) ? zu + (size_t)s0 * kH : zi + (size_t)(s0 - kNU) * kH;
      r1 = (s1 < kNU) ? zu + (size_t)s1 * kH : zi + (size_t)(s1 - kNU) * kH;
    } else {
      r0 = zu + (size_t)s0 * kH;
      r1 = zu + (size_t)s1 * kH;
    }
    float4 v0 = *reinterpret_cast<const float4*>(r0 + lane * 4);
    float4 v1 = *reinterpret_cast<const float4*>(r1 + lane * 4);
    acc.x += v0.x + v1.x; acc.y += v0.y + v1.y;
    acc.z += v0.z + v1.z; acc.w += v0.w + v1.w;
  }
  if (i < e) {
    int s0 = eids[i];
    const float* r0;
    if (SPLIT) r0 = (s0 < kNU) ? zu + (size_t)s0 * kH : zi + (size_t)(s0 - kNU) * kH;
    else r0 = zu + (size_t)s0 * kH;
    float4 v0 = *reinterpret_cast<const float4*>(r0 + lane * 4);
    acc.x += v0.x; acc.y += v0.y; acc.z += v0.z; acc.w += v0.w;
  }
  const float sc = inv[row];
  float4 r = make_float4(acc.x * sc, acc.y * sc, acc.z * sc, acc.w * sc);
  *reinterpret_cast<float4*>(aggOut + (size_t)row * kH + lane * 4) = r;
}

// ---- GEMM helpers: 8 rows, KC-wide panel, weights from LDS ----
// A addresses are wave-uniform (scalar loads); w per-lane from LDS.
template <int KC>
__device__ inline void panel8(const float* __restrict__ P, int rb, int o,
                              const float* __restrict__ wlds, int kbase,
                              int lane, float* __restrict__ acc) {
  const float* ab[8];
#pragma unroll
  for (int r = 0; r < 8; ++r) ab[r] = uptr(P + (size_t)(rb + r) * kH + o);
#pragma unroll
  for (int kc = 0; kc < KC; kc += 4) {
    float4 av[8];
#pragma unroll
    for (int r = 0; r < 8; ++r) av[r] = *reinterpret_cast<const float4*>(ab[r] + kc);
#pragma unroll
    for (int j = 0; j < 4; ++j) {
      float w = wlds[(kbase + kc + j) * 64 + lane];
#pragma unroll
      for (int r = 0; r < 8; ++r) {
        float a = (j == 0) ? av[r].x : (j == 1) ? av[r].y : (j == 2) ? av[r].z : av[r].w;
        acc[r] = fmaf(a, w, acc[r]);
      }
    }
  }
}

template <int KC, bool SPLITX>
__device__ inline void panelX8(const float* __restrict__ Xu, const float* __restrict__ Xi,
                               int rb, int oz, const float* __restrict__ wlds,
                               int lane, float* __restrict__ acc) {
  const float* ab[8];
#pragma unroll
  for (int r = 0; r < 8; ++r) {
    int rr = rb + r;
    const float* p;
    if (SPLITX) p = (rr < kNU) ? Xu + (size_t)rr * kH : Xi + (size_t)(rr - kNU) * kH;
    else        p = Xu + (size_t)rr * kH;
    ab[r] = uptr(p + oz);
  }
#pragma unroll
  for (int kc = 0; kc < KC; kc += 4) {
    float4 av[8];
#pragma unroll
    for (int r = 0; r < 8; ++r) av[r] = *reinterpret_cast<const float4*>(ab[r] + kc);
#pragma unroll
    for (int j = 0; j < 4; ++j) {
      float w = wlds[(kc + j) * 64 + lane];
#pragma unroll
      for (int r = 0; r < 8; ++r) {
        float a = (j == 0) ? av[r].x : (j == 1) ? av[r].y : (j == 2) ? av[r].z : av[r].w;
        acc[r] = fmaf(a, w, acc[r]);
      }
    }
  }
}

// ---- fused GEMM half-layer ----
// out[:, ooff:+64] = relu( P1[:, o1:+64] @ W1[0:64,:] + P2[:, o2:+64] @ W1[64:128,:]
//                          + X[:, oz:+K2] @ W2 + bias )
// Block: 256 threads = 4 waves; 64 rows/block, 16 rows/wave (two 8-row halves).
// In-place safe (out may alias Xu): reads before barrier, writes after; each wave
// only touches its own rows (clamped tail rows duplicate identical work).
template <int K2, bool SPLITX>
__global__ __launch_bounds__(256) void gemm2(
    const float* __restrict__ P1, int o1,
    const float* __restrict__ P2, int o2,
    const float* __restrict__ W1,   // 128 x 64
    const float* __restrict__ Xu, const float* __restrict__ Xi, int oz,
    const float* __restrict__ W2,   // K2 x 64
    const float* __restrict__ bias,
    float* __restrict__ out, int ooff) {
  __shared__ float wl[128 * 64];
  __shared__ float wr[K2 * 64];
  const int tid = threadIdx.x;
  for (int i = tid; i < 128 * 64; i += 256) wl[i] = W1[i];
  for (int i = tid; i < K2 * 64; i += 256) wr[i] = W2[i];
  __syncthreads();

  const int lane = tid & 63;
  const int wv = tid >> 6;
  int r0 = blockIdx.x * 64 + wv * 16;
  if (r0 > kN - 16) r0 = kN - 16;

  const float b = bias[lane];
  float acc[16];
#pragma unroll
  for (int i = 0; i < 16; ++i) acc[i] = b;

  for (int h = 0; h < 2; ++h) {
    const int rb = r0 + h * 8;
    float* a8 = acc + h * 8;
    panel8<64>(P1, rb, o1, wl, 0, lane, a8);
    panel8<64>(P2, rb, o2, wl, 64, lane, a8);
    panelX8<K2, SPLITX>(Xu, Xi, rb, oz, wr, lane, a8);
  }

  __syncthreads();  // all X reads complete before in-place writes
  float* o = out + (size_t)r0 * kH + ooff + lane;
#pragma unroll
  for (int r = 0; r < 16; ++r) o[(size_t)r * kH] = fmaxf(acc[r], 0.0f);
}

inline float* align16(void* p) {
  return (float*)(((uintptr_t)p + 15) & ~(uintptr_t)15);
}

}  // namespace

extern "C" void kernel_launch(void* const* d_in, const int* in_sizes, int n_in,
                              void* d_out, int out_size, void* d_ws, size_t ws_size,
                              hipStream_t stream) {
  const int*   pos     = (const int*)d_in[0];
  const int*   neg     = (const int*)d_in[1];
  const float* users   = (const float*)d_in[2];
  const float* items   = (const float*)d_in[3];
  const float* c1_wpl  = (const float*)d_in[4];
  const float* c1_wpr  = (const float*)d_in[5];
  const float* c1_bpr  = (const float*)d_in[6];
  const float* c1_wnl  = (const float*)d_in[7];
  const float* c1_wnr  = (const float*)d_in[8];
  const float* c1_bnr  = (const float*)d_in[9];
  const float* cw_pl   = (const float*)d_in[10];
  const float* cw_pr   = (const float*)d_in[11];
  const float* cb_pr   = (const float*)d_in[12];
  const float* cw_nl   = (const float*)d_in[13];
  const float* cw_nr   = (const float*)d_in[14];
  const float* cb_nr   = (const float*)d_in[15];
  float* out = (float*)d_out;

  const int* pos_src = pos;
  const int* pos_dst = pos + kEP;
  const int* neg_src = neg;
  const int* neg_dst = neg + kEN;

  // ---- workspace layout ----
  float* invp = (float*)d_ws;
  float* invn = invp + kN;
  int* degp   = (int*)(invn + kN);
  int* degn   = degp + kN;
  int* offp   = degn + kN;
  int* offn   = offp + kN + 1;
  int* sums   = offn + kN + 1;
  int* eidp   = sums + 256;
  int* eidn   = eidp + kEP;
  float* aggP = align16(eidn + kEN);
  float* aggN = aggP + (size_t)kN * kH;
  const size_t need = (size_t)((char*)(aggN + (size_t)kN * kH) - (char*)d_ws);
  if (ws_size < need) return;

  const int nbP = (kN + SCAN_TILE - 1) / SCAN_TILE;

  // ---- degree counts + inverses ----
  hipMemsetAsync(degp, 0, (size_t)2 * kN * sizeof(int), stream);
  count_kernel<<<(kEP + 255) / 256, 256, 0, stream>>>(pos_dst, kEP, degp);
  count_kernel<<<(kEN + 255) / 256, 256, 0, stream>>>(neg_dst, kEN, degn);
  inv_kernel<<<(kN + 255) / 256, 256, 0, stream>>>(degp, invp, kN);
  inv_kernel<<<(kN + 255) / 256, 256, 0, stream>>>(degn, invn, kN);

  // ---- CSR build (pos) ----
  scan_partial<<<nbP, SCAN_BS, 0, stream>>>(degp, kN, offp, sums);
  scan_sums<<<1, SCAN_BS, 0, stream>>>(sums, nbP);
  scan_add<<<(kN + 255) / 256, 256, 0, stream>>>(offp, kN, sums);
  hipMemcpyAsync(degp, offp, (size_t)kN * sizeof(int), hipMemcpyDeviceToDevice, stream);
  fill_kernel<<<(kEP + 255) / 256, 256, 0, stream>>>(pos_src, pos_dst, kEP, degp, eidp);

  // ---- CSR build (neg) ----
  scan_partial<<<nbP, SCAN_BS, 0, stream>>>(degn, kN, offn, sums);
  scan_sums<<<1, SCAN_BS, 0, stream>>>(sums, nbP);
  scan_add<<<(kN + 255) / 256, 256, 0, stream>>>(offn, kN, sums);
  hipMemcpyAsync(degn, offn, (size_t)kN * sizeof(int), hipMemcpyDeviceToDevice, stream);
  fill_kernel<<<(kEN + 255) / 256, 256, 0, stream>>>(neg_src, neg_dst, kEN, degn, eidn);

  const int gA = (kN + 7) / 8;
  const int gG = (kN + 63) / 64;

  // ---- layer 1 ----
  agg_csr<true><<<gA, 256, 0, stream>>>(offp, eidp, invp, users, items, aggP);
  agg_csr<true><<<gA, 256, 0, stream>>>(offn, eidn, invn, users, items, aggN);
  gemm2<128, true><<<gG, 256, 0, stream>>>(aggP, 0, aggP, 64, c1_wpl,
                                           users, items, 0, c1_wpr, c1_bpr, out, 0);
  gemm2<128, true><<<gG, 256, 0, stream>>>(aggN, 0, aggN, 64, c1_wnl,
                                           users, items, 0, c1_wnr, c1_bnr, out, 64);

  // ---- inner layers: z lives in d_out, updated in place ----
  for (int l = 0; l < kL; ++l) {
    const float* wpl = cw_pl + (size_t)l * kH * 64;
    const float* wpr = cw_pr + (size_t)l * 64 * 64;
    const float* bpr = cb_pr + (size_t)l * 64;
    const float* wnl = cw_nl + (size_t)l * kH * 64;
    const float* wnr = cw_nr + (size_t)l * 64 * 64;
    const float* bnr = cb_nr + (size_t)l * 64;

    // aggP = mean_p(z) = [a_pp | a_np]; aggN = mean_n(z) = [a_pn | a_nn]
    agg_csr<false><<<gA, 256, 0, stream>>>(offp, eidp, invp, out, nullptr, aggP);
    agg_csr<false><<<gA, 256, 0, stream>>>(offn, eidn, invn, out, nullptr, aggN);

    // out_pos = relu(concat(a_pp, a_nn) @ wpl + zp @ wpr + bpr)
    gemm2<64, false><<<gG, 256, 0, stream>>>(aggP, 0, aggN, 64, wpl,
                                             out, nullptr, 0, wpr, bpr, out, 0);
    // out_neg = relu(concat(a_np, a_pn) @ wnl + zn @ wnr + bnr)
    gemm2<64, false><<<gG, 256, 0, stream>>>(aggP, 64, aggN, 0, wnl,
                                             out, nullptr, 64, wnr, bnr, out, 64);
  }
}

// Round 4
// 2526.600 us; speedup vs baseline: 1.9131x; 1.9131x over previous
//
#include <hip/hip_runtime.h>

namespace {

constexpr int kNU = 100000;
constexpr int kNI = 50000;
constexpr int kN  = 150000;
constexpr int kH  = 128;
constexpr int kEP = 2000000;
constexpr int kEN = 1000000;
constexpr int kL  = 2;

constexpr int SCAN_BS = 256;
constexpr int SCAN_IT = 4;
constexpr int SCAN_TILE = SCAN_BS * SCAN_IT;

// ---- degree counting ----
__global__ void count_kernel(const int* __restrict__ dst, int E, int* __restrict__ deg) {
  int t = blockIdx.x * blockDim.x + threadIdx.x;
  if (t < E) atomicAdd(&deg[dst[t]], 1);
}

__global__ void inv_kernel(const int* __restrict__ deg, float* __restrict__ inv, int n) {
  int t = blockIdx.x * blockDim.x + threadIdx.x;
  if (t < n) inv[t] = 1.0f / fmaxf((float)deg[t], 1.0f);
}

// ---- 3-phase exclusive scan ----
__global__ void scan_partial(const int* __restrict__ deg, int n,
                             int* __restrict__ off, int* __restrict__ sums) {
  __shared__ int sh[SCAN_BS];
  const int t = threadIdx.x;
  const int base = blockIdx.x * SCAN_TILE;
  int v[SCAN_IT];
  int run = 0;
#pragma unroll
  for (int j = 0; j < SCAN_IT; ++j) {
    int idx = base + t * SCAN_IT + j;
    v[j] = (idx < n) ? deg[idx] : 0;
    run += v[j];
  }
  sh[t] = run;
  __syncthreads();
  for (int d = 1; d < SCAN_BS; d <<= 1) {
    int x = (t >= d) ? sh[t - d] : 0;
    __syncthreads();
    sh[t] += x;
    __syncthreads();
  }
  int acc = sh[t] - run;
  if (t == SCAN_BS - 1) sums[blockIdx.x] = sh[t];
#pragma unroll
  for (int j = 0; j < SCAN_IT; ++j) {
    int idx = base + t * SCAN_IT + j;
    acc += v[j];
    if (idx < n) off[idx + 1] = acc;
  }
}

__global__ void scan_sums(int* __restrict__ sums, int nb) {
  __shared__ int sh[SCAN_BS];
  const int t = threadIdx.x;
  int v = (t < nb) ? sums[t] : 0;
  sh[t] = v;
  __syncthreads();
  for (int d = 1; d < SCAN_BS; d <<= 1) {
    int x = (t >= d) ? sh[t - d] : 0;
    __syncthreads();
    sh[t] += x;
    __syncthreads();
  }
  if (t < nb) sums[t] = sh[t] - v;
}

__global__ void scan_add(int* __restrict__ off, int n, const int* __restrict__ sums) {
  int t = blockIdx.x * blockDim.x + threadIdx.x;
  if (t == 0) off[0] = 0;
  if (t < n) off[t + 1] += sums[t / SCAN_TILE];
}

// ---- CSR fill ----
__global__ void fill_kernel(const int* __restrict__ src, const int* __restrict__ dst, int E,
                            int* __restrict__ cursor, int* __restrict__ eids) {
  int t = blockIdx.x * blockDim.x + threadIdx.x;
  if (t < E) {
    int p = atomicAdd(&cursor[dst[t]], 1);
    eids[p] = src[t];
  }
}

// ---- CSR gather-mean (full 128-wide) ----
template <bool SPLIT>
__global__ __launch_bounds__(256) void agg_csr(
    const int* __restrict__ off, const int* __restrict__ eids,
    const float* __restrict__ inv,
    const float* __restrict__ zu, const float* __restrict__ zi,
    float* __restrict__ aggOut) {
  const int g = threadIdx.x >> 5;
  const int lane = threadIdx.x & 31;
  const int row = blockIdx.x * 8 + g;
  if (row >= kN) return;
  const int s = off[row], e = off[row + 1];
  float4 acc = make_float4(0.f, 0.f, 0.f, 0.f);
  int i = s;
  for (; i + 2 <= e; i += 2) {
    int s0 = eids[i], s1 = eids[i + 1];
    const float* r0;
    const float* r1;
    if (SPLIT) {
      r0 = (s0 < kNU) ? zu + (size_t)s0 * kH : zi + (size_t)(s0 - kNU) * kH;
      r1 = (s1 < kNU) ? zu + (size_t)s1 * kH : zi + (size_t)(s1 - kNU) * kH;
    } else {
      r0 = zu + (size_t)s0 * kH;
      r1 = zu + (size_t)s1 * kH;
    }
    float4 v0 = *reinterpret_cast<const float4*>(r0 + lane * 4);
    float4 v1 = *reinterpret_cast<const float4*>(r1 + lane * 4);
    acc.x += v0.x + v1.x; acc.y += v0.y + v1.y;
    acc.z += v0.z + v1.z; acc.w += v0.w + v1.w;
  }
  if (i < e) {
    int s0 = eids[i];
    const float* r0;
    if (SPLIT) r0 = (s0 < kNU) ? zu + (size_t)s0 * kH : zi + (size_t)(s0 - kNU) * kH;
    else r0 = zu + (size_t)s0 * kH;
    float4 v0 = *reinterpret_cast<const float4*>(r0 + lane * 4);
    acc.x += v0.x; acc.y += v0.y; acc.z += v0.z; acc.w += v0.w;
  }
  const float sc = inv[row];
  float4 r = make_float4(acc.x * sc, acc.y * sc, acc.z * sc, acc.w * sc);
  *reinterpret_cast<float4*>(aggOut + (size_t)row * kH + lane * 4) = r;
}

// ---- fused GEMM half-layer ----
// out[:, ooff:+64] = relu( P1[:, o1:+64] @ W1[0:64,:] + P2[:, o2:+64] @ W1[64:128,:]
//                          + X[:, oz:+K2] @ W2 + bias )
// 256 threads = 4 waves; 32 rows/block, 8 rows/thread (lane = output col).
// W1 staged in 32KB LDS; W2 streamed from global (L1/L2-hot).
// In-place safe: each block reads X only from its own rows before the barrier,
// writes after; tail rows use clamped loads + guarded writes.
template <int K2, bool SPLITX>
__global__ __launch_bounds__(256, 4) void gemm2(
    const float* __restrict__ P1, int o1,
    const float* __restrict__ P2, int o2,
    const float* __restrict__ W1,   // 128 x 64
    const float* __restrict__ Xu, const float* __restrict__ Xi, int oz,
    const float* __restrict__ W2,   // K2 x 64
    const float* __restrict__ bias,
    float* __restrict__ out, int ooff) {
  __shared__ float wl[128 * 64];
  const int tid = threadIdx.x;
  {
    const float4* s4 = reinterpret_cast<const float4*>(W1);
    float4* d4 = reinterpret_cast<float4*>(wl);
#pragma unroll
    for (int i = 0; i < 8; ++i) d4[tid + 256 * i] = s4[tid + 256 * i];
  }
  __syncthreads();

  const int lane = tid & 63;
  const int wv = tid >> 6;
  const int rb = blockIdx.x * 32 + wv * 8;

  int roff[8];
#pragma unroll
  for (int r = 0; r < 8; ++r) {
    int rr = rb + r;
    if (rr >= kN) rr = kN - 1;
    roff[r] = rr * kH;
  }

  const float b = bias[lane];
  float acc[8];
#pragma unroll
  for (int r = 0; r < 8; ++r) acc[r] = b;

  // ---- panel 1: P1 against W1 rows [0,64) ----
#pragma unroll 2
  for (int kc = 0; kc < 64; kc += 4) {
    float4 av[8];
#pragma unroll
    for (int r = 0; r < 8; ++r)
      av[r] = *reinterpret_cast<const float4*>(P1 + roff[r] + o1 + kc);
#pragma unroll
    for (int j = 0; j < 4; ++j) {
      float w = wl[(kc + j) * 64 + lane];
#pragma unroll
      for (int r = 0; r < 8; ++r) {
        float a = (j == 0) ? av[r].x : (j == 1) ? av[r].y : (j == 2) ? av[r].z : av[r].w;
        acc[r] = fmaf(a, w, acc[r]);
      }
    }
  }

  // ---- panel 2: P2 against W1 rows [64,128) ----
#pragma unroll 2
  for (int kc = 0; kc < 64; kc += 4) {
    float4 av[8];
#pragma unroll
    for (int r = 0; r < 8; ++r)
      av[r] = *reinterpret_cast<const float4*>(P2 + roff[r] + o2 + kc);
#pragma unroll
    for (int j = 0; j < 4; ++j) {
      float w = wl[(64 + kc + j) * 64 + lane];
#pragma unroll
      for (int r = 0; r < 8; ++r) {
        float a = (j == 0) ? av[r].x : (j == 1) ? av[r].y : (j == 2) ? av[r].z : av[r].w;
        acc[r] = fmaf(a, w, acc[r]);
      }
    }
  }

  // ---- panel X: X against W2 (weights from global, L1/L2-hot) ----
  if constexpr (SPLITX) {
    const float* px[8];
#pragma unroll
    for (int r = 0; r < 8; ++r) {
      int rr = rb + r;
      if (rr >= kN) rr = kN - 1;
      px[r] = ((rr < kNU) ? Xu + (size_t)rr * kH : Xi + (size_t)(rr - kNU) * kH) + oz;
    }
#pragma unroll 2
    for (int kc = 0; kc < K2; kc += 4) {
      float4 av[8];
#pragma unroll
      for (int r = 0; r < 8; ++r)
        av[r] = *reinterpret_cast<const float4*>(px[r] + kc);
      float w4[4];
#pragma unroll
      for (int j = 0; j < 4; ++j) w4[j] = W2[(kc + j) * 64 + lane];
#pragma unroll
      for (int j = 0; j < 4; ++j) {
#pragma unroll
        for (int r = 0; r < 8; ++r) {
          float a = (j == 0) ? av[r].x : (j == 1) ? av[r].y : (j == 2) ? av[r].z : av[r].w;
          acc[r] = fmaf(a, w4[j], acc[r]);
        }
      }
    }
  } else {
#pragma unroll 2
    for (int kc = 0; kc < K2; kc += 4) {
      float4 av[8];
#pragma unroll
      for (int r = 0; r < 8; ++r)
        av[r] = *reinterpret_cast<const float4*>(Xu + roff[r] + oz + kc);
      float w4[4];
#pragma unroll
      for (int j = 0; j < 4; ++j) w4[j] = W2[(kc + j) * 64 + lane];
#pragma unroll
      for (int j = 0; j < 4; ++j) {
#pragma unroll
        for (int r = 0; r < 8; ++r) {
          float a = (j == 0) ? av[r].x : (j == 1) ? av[r].y : (j == 2) ? av[r].z : av[r].w;
          acc[r] = fmaf(a, w4[j], acc[r]);
        }
      }
    }
  }

  __syncthreads();  // all X reads complete before in-place writes
#pragma unroll
  for (int r = 0; r < 8; ++r) {
    int rr = rb + r;
    if (rr < kN) out[(size_t)rr * kH + ooff + lane] = fmaxf(acc[r], 0.0f);
  }
}

inline float* align16(void* p) {
  return (float*)(((uintptr_t)p + 15) & ~(uintptr_t)15);
}

}  // namespace

extern "C" void kernel_launch(void* const* d_in, const int* in_sizes, int n_in,
                              void* d_out, int out_size, void* d_ws, size_t ws_size,
                              hipStream_t stream) {
  const int*   pos     = (const int*)d_in[0];
  const int*   neg     = (const int*)d_in[1];
  const float* users   = (const float*)d_in[2];
  const float* items   = (const float*)d_in[3];
  const float* c1_wpl  = (const float*)d_in[4];
  const float* c1_wpr  = (const float*)d_in[5];
  const float* c1_bpr  = (const float*)d_in[6];
  const float* c1_wnl  = (const float*)d_in[7];
  const float* c1_wnr  = (const float*)d_in[8];
  const float* c1_bnr  = (const float*)d_in[9];
  const float* cw_pl   = (const float*)d_in[10];
  const float* cw_pr   = (const float*)d_in[11];
  const float* cb_pr   = (const float*)d_in[12];
  const float* cw_nl   = (const float*)d_in[13];
  const float* cw_nr   = (const float*)d_in[14];
  const float* cb_nr   = (const float*)d_in[15];
  float* out = (float*)d_out;

  const int* pos_src = pos;
  const int* pos_dst = pos + kEP;
  const int* neg_src = neg;
  const int* neg_dst = neg + kEN;

  // ---- workspace layout ----
  float* invp = (float*)d_ws;
  float* invn = invp + kN;
  int* degp   = (int*)(invn + kN);
  int* degn   = degp + kN;
  int* offp   = degn + kN;
  int* offn   = offp + kN + 1;
  int* sums   = offn + kN + 1;
  int* eidp   = sums + 256;
  int* eidn   = eidp + kEP;
  float* aggP = align16(eidn + kEN);
  float* aggN = aggP + (size_t)kN * kH;
  const size_t need = (size_t)((char*)(aggN + (size_t)kN * kH) - (char*)d_ws);
  if (ws_size < need) return;

  const int nbP = (kN + SCAN_TILE - 1) / SCAN_TILE;

  // ---- degree counts + inverses ----
  hipMemsetAsync(degp, 0, (size_t)2 * kN * sizeof(int), stream);
  count_kernel<<<(kEP + 255) / 256, 256, 0, stream>>>(pos_dst, kEP, degp);
  count_kernel<<<(kEN + 255) / 256, 256, 0, stream>>>(neg_dst, kEN, degn);
  inv_kernel<<<(kN + 255) / 256, 256, 0, stream>>>(degp, invp, kN);
  inv_kernel<<<(kN + 255) / 256, 256, 0, stream>>>(degn, invn, kN);

  // ---- CSR build (pos) ----
  scan_partial<<<nbP, SCAN_BS, 0, stream>>>(degp, kN, offp, sums);
  scan_sums<<<1, SCAN_BS, 0, stream>>>(sums, nbP);
  scan_add<<<(kN + 255) / 256, 256, 0, stream>>>(offp, kN, sums);
  hipMemcpyAsync(degp, offp, (size_t)kN * sizeof(int), hipMemcpyDeviceToDevice, stream);
  fill_kernel<<<(kEP + 255) / 256, 256, 0, stream>>>(pos_src, pos_dst, kEP, degp, eidp);

  // ---- CSR build (neg) ----
  scan_partial<<<nbP, SCAN_BS, 0, stream>>>(degn, kN, offn, sums);
  scan_sums<<<1, SCAN_BS, 0, stream>>>(sums, nbP);
  scan_add<<<(kN + 255) / 256, 256, 0, stream>>>(offn, kN, sums);
  hipMemcpyAsync(degn, offn, (size_t)kN * sizeof(int), hipMemcpyDeviceToDevice, stream);
  fill_kernel<<<(kEN + 255) / 256, 256, 0, stream>>>(neg_src, neg_dst, kEN, degn, eidn);

  const int gA = (kN + 7) / 8;
  const int gG = (kN + 31) / 32;

  // ---- layer 1 ----
  agg_csr<true><<<gA, 256, 0, stream>>>(offp, eidp, invp, users, items, aggP);
  agg_csr<true><<<gA, 256, 0, stream>>>(offn, eidn, invn, users, items, aggN);
  gemm2<128, true><<<gG, 256, 0, stream>>>(aggP, 0, aggP, 64, c1_wpl,
                                           users, items, 0, c1_wpr, c1_bpr, out, 0);
  gemm2<128, true><<<gG, 256, 0, stream>>>(aggN, 0, aggN, 64, c1_wnl,
                                           users, items, 0, c1_wnr, c1_bnr, out, 64);

  // ---- inner layers: z lives in d_out, updated in place ----
  for (int l = 0; l < kL; ++l) {
    const float* wpl = cw_pl + (size_t)l * kH * 64;
    const float* wpr = cw_pr + (size_t)l * 64 * 64;
    const float* bpr = cb_pr + (size_t)l * 64;
    const float* wnl = cw_nl + (size_t)l * kH * 64;
    const float* wnr = cw_nr + (size_t)l * 64 * 64;
    const float* bnr = cb_nr + (size_t)l * 64;

    // aggP = mean_p(z) = [a_pp | a_np]; aggN = mean_n(z) = [a_pn | a_nn]
    agg_csr<false><<<gA, 256, 0, stream>>>(offp, eidp, invp, out, nullptr, aggP);
    agg_csr<false><<<gA, 256, 0, stream>>>(offn, eidn, invn, out, nullptr, aggN);

    // out_pos = relu(concat(a_pp, a_nn) @ wpl + zp @ wpr + bpr)
    gemm2<64, false><<<gG, 256, 0, stream>>>(aggP, 0, aggN, 64, wpl,
                                             out, nullptr, 0, wpr, bpr, out, 0);
    // out_neg = relu(concat(a_np, a_pn) @ wnl + zn @ wnr + bnr)
    gemm2<64, false><<<gG, 256, 0, stream>>>(aggP, 64, aggN, 0, wnl,
                                             out, nullptr, 64, wnr, bnr, out, 64);
  }
}

// Round 5
// 1766.070 us; speedup vs baseline: 2.7370x; 1.4306x over previous
//
#include <hip/hip_runtime.h>

namespace {

constexpr int kNU = 100000;
constexpr int kNI = 50000;
constexpr int kN  = 150000;
constexpr int kH  = 128;
constexpr int kEP = 2000000;
constexpr int kEN = 1000000;
constexpr int kL  = 2;

constexpr int SCAN_BS = 256;
constexpr int SCAN_IT = 4;
constexpr int SCAN_TILE = SCAN_BS * SCAN_IT;

// ---- degree counting ----
__global__ void count_kernel(const int* __restrict__ dst, int E, int* __restrict__ deg) {
  int t = blockIdx.x * blockDim.x + threadIdx.x;
  if (t < E) atomicAdd(&deg[dst[t]], 1);
}

__global__ void inv_kernel(const int* __restrict__ deg, float* __restrict__ inv, int n) {
  int t = blockIdx.x * blockDim.x + threadIdx.x;
  if (t < n) inv[t] = 1.0f / fmaxf((float)deg[t], 1.0f);
}

// ---- 3-phase exclusive scan ----
__global__ void scan_partial(const int* __restrict__ deg, int n,
                             int* __restrict__ off, int* __restrict__ sums) {
  __shared__ int sh[SCAN_BS];
  const int t = threadIdx.x;
  const int base = blockIdx.x * SCAN_TILE;
  int v[SCAN_IT];
  int run = 0;
#pragma unroll
  for (int j = 0; j < SCAN_IT; ++j) {
    int idx = base + t * SCAN_IT + j;
    v[j] = (idx < n) ? deg[idx] : 0;
    run += v[j];
  }
  sh[t] = run;
  __syncthreads();
  for (int d = 1; d < SCAN_BS; d <<= 1) {
    int x = (t >= d) ? sh[t - d] : 0;
    __syncthreads();
    sh[t] += x;
    __syncthreads();
  }
  int acc = sh[t] - run;
  if (t == SCAN_BS - 1) sums[blockIdx.x] = sh[t];
#pragma unroll
  for (int j = 0; j < SCAN_IT; ++j) {
    int idx = base + t * SCAN_IT + j;
    acc += v[j];
    if (idx < n) off[idx + 1] = acc;
  }
}

__global__ void scan_sums(int* __restrict__ sums, int nb) {
  __shared__ int sh[SCAN_BS];
  const int t = threadIdx.x;
  int v = (t < nb) ? sums[t] : 0;
  sh[t] = v;
  __syncthreads();
  for (int d = 1; d < SCAN_BS; d <<= 1) {
    int x = (t >= d) ? sh[t - d] : 0;
    __syncthreads();
    sh[t] += x;
    __syncthreads();
  }
  if (t < nb) sums[t] = sh[t] - v;
}

__global__ void scan_add(int* __restrict__ off, int n, const int* __restrict__ sums) {
  int t = blockIdx.x * blockDim.x + threadIdx.x;
  if (t == 0) off[0] = 0;
  if (t < n) off[t + 1] += sums[t / SCAN_TILE];
}

// ---- CSR fill ----
__global__ void fill_kernel(const int* __restrict__ src, const int* __restrict__ dst, int E,
                            int* __restrict__ cursor, int* __restrict__ eids) {
  int t = blockIdx.x * blockDim.x + threadIdx.x;
  if (t < E) {
    int p = atomicAdd(&cursor[dst[t]], 1);
    eids[p] = src[t];
  }
}

// ---- CSR gather-mean (full 128-wide) ----
template <bool SPLIT>
__global__ __launch_bounds__(256) void agg_csr(
    const int* __restrict__ off, const int* __restrict__ eids,
    const float* __restrict__ inv,
    const float* __restrict__ zu, const float* __restrict__ zi,
    float* __restrict__ aggOut) {
  const int g = threadIdx.x >> 5;
  const int lane = threadIdx.x & 31;
  const int row = blockIdx.x * 8 + g;
  if (row >= kN) return;
  const int s = off[row], e = off[row + 1];
  float4 acc = make_float4(0.f, 0.f, 0.f, 0.f);
  int i = s;
  for (; i + 2 <= e; i += 2) {
    int s0 = eids[i], s1 = eids[i + 1];
    const float* r0;
    const float* r1;
    if (SPLIT) {
      r0 = (s0 < kNU) ? zu + (size_t)s0 * kH : zi + (size_t)(s0 - kNU) * kH;
      r1 = (s1 < kNU) ? zu + (size_t)s1 * kH : zi + (size_t)(s1 - kNU) * kH;
    } else {
      r0 = zu + (size_t)s0 * kH;
      r1 = zu + (size_t)s1 * kH;
    }
    float4 v0 = *reinterpret_cast<const float4*>(r0 + lane * 4);
    float4 v1 = *reinterpret_cast<const float4*>(r1 + lane * 4);
    acc.x += v0.x + v1.x; acc.y += v0.y + v1.y;
    acc.z += v0.z + v1.z; acc.w += v0.w + v1.w;
  }
  if (i < e) {
    int s0 = eids[i];
    const float* r0;
    if (SPLIT) r0 = (s0 < kNU) ? zu + (size_t)s0 * kH : zi + (size_t)(s0 - kNU) * kH;
    else r0 = zu + (size_t)s0 * kH;
    float4 v0 = *reinterpret_cast<const float4*>(r0 + lane * 4);
    acc.x += v0.x; acc.y += v0.y; acc.z += v0.z; acc.w += v0.w;
  }
  const float sc = inv[row];
  float4 r = make_float4(acc.x * sc, acc.y * sc, acc.z * sc, acc.w * sc);
  *reinterpret_cast<float4*>(aggOut + (size_t)row * kH + lane * 4) = r;
}

// ---- fused GEMM half-layer, LDS-staged A ----
// out[:, ooff:+64] = relu( P1[:, o1:+64] @ W1[0:64,:] + P2[:, o2:+64] @ W1[64:128,:]
//                          + X[:, oz:+K2] @ W2 + bias )
// 256 threads = 4 waves; 32 rows/block, 8 rows/thread (lane = output col).
// A-tile (32 x (128+K2)) staged cooperatively into LDS with coalesced float4
// loads (1KB useful/VMEM instr vs 16B broadcast) -> VMEM issue drops ~50x.
// W1 in LDS; W2 streamed from global (L2-hot).
// In-place safe: all X reads happen in the staging phase (own rows only),
// barrier, compute from LDS, writes to own rows.
template <int K2, bool SPLITX>
__global__ __launch_bounds__(256) void gemm2(
    const float* __restrict__ P1, int o1,
    const float* __restrict__ P2, int o2,
    const float* __restrict__ W1,   // 128 x 64
    const float* __restrict__ Xu, const float* __restrict__ Xi, int oz,
    const float* __restrict__ W2,   // K2 x 64
    const float* __restrict__ bias,
    float* __restrict__ out, int ooff) {
  constexpr int TW = 128 + K2;     // tile width (192 or 256)
  constexpr int TW4 = TW / 4;      // float4s per row
  __shared__ float wl[128 * 64];   // 32KB
  __shared__ float at[32 * TW];    // 24KB or 32KB
  const int tid = threadIdx.x;
  const int rb0 = blockIdx.x * 32;

  // stage W1
  {
    const float4* s4 = reinterpret_cast<const float4*>(W1);
    float4* d4 = reinterpret_cast<float4*>(wl);
#pragma unroll
    for (int i = 0; i < 8; ++i) d4[tid + 256 * i] = s4[tid + 256 * i];
  }
  // stage A-tile: [row][0:64)=P1 slice, [64:128)=P2 slice, [128:TW)=X slice
#pragma unroll
  for (int i = tid; i < 32 * TW4; i += 256) {
    int row = i / TW4;
    int col = (i - row * TW4) * 4;
    int rr = rb0 + row;
    if (rr >= kN) rr = kN - 1;
    const float* srcp;
    if (col < 64) {
      srcp = P1 + (size_t)rr * kH + o1 + col;
    } else if (col < 128) {
      srcp = P2 + (size_t)rr * kH + o2 + (col - 64);
    } else {
      if (SPLITX)
        srcp = ((rr < kNU) ? Xu + (size_t)rr * kH : Xi + (size_t)(rr - kNU) * kH)
               + oz + (col - 128);
      else
        srcp = Xu + (size_t)rr * kH + oz + (col - 128);
    }
    *reinterpret_cast<float4*>(&at[row * TW + col]) =
        *reinterpret_cast<const float4*>(srcp);
  }
  __syncthreads();

  const int lane = tid & 63;
  const int wv = tid >> 6;
  const float* arow0 = at + (wv * 8) * TW;

  const float b = bias[lane];
  float acc[8];
#pragma unroll
  for (int r = 0; r < 8; ++r) acc[r] = b;

  // ---- panel 1: A cols [0,64) x W1 rows [0,64) ----
#pragma unroll 2
  for (int kc = 0; kc < 64; kc += 4) {
    float4 av[8];
#pragma unroll
    for (int r = 0; r < 8; ++r)
      av[r] = *reinterpret_cast<const float4*>(arow0 + r * TW + kc);
#pragma unroll
    for (int j = 0; j < 4; ++j) {
      float w = wl[(kc + j) * 64 + lane];
#pragma unroll
      for (int r = 0; r < 8; ++r) {
        float a = (j == 0) ? av[r].x : (j == 1) ? av[r].y : (j == 2) ? av[r].z : av[r].w;
        acc[r] = fmaf(a, w, acc[r]);
      }
    }
  }

  // ---- panel 2: A cols [64,128) x W1 rows [64,128) ----
#pragma unroll 2
  for (int kc = 0; kc < 64; kc += 4) {
    float4 av[8];
#pragma unroll
    for (int r = 0; r < 8; ++r)
      av[r] = *reinterpret_cast<const float4*>(arow0 + r * TW + 64 + kc);
#pragma unroll
    for (int j = 0; j < 4; ++j) {
      float w = wl[(64 + kc + j) * 64 + lane];
#pragma unroll
      for (int r = 0; r < 8; ++r) {
        float a = (j == 0) ? av[r].x : (j == 1) ? av[r].y : (j == 2) ? av[r].z : av[r].w;
        acc[r] = fmaf(a, w, acc[r]);
      }
    }
  }

  // ---- panel X: A cols [128,TW) x W2 (streamed from global, L2-hot) ----
#pragma unroll 2
  for (int kc = 0; kc < K2; kc += 4) {
    float4 av[8];
#pragma unroll
    for (int r = 0; r < 8; ++r)
      av[r] = *reinterpret_cast<const float4*>(arow0 + r * TW + 128 + kc);
    float w4[4];
#pragma unroll
    for (int j = 0; j < 4; ++j) w4[j] = W2[(kc + j) * 64 + lane];
#pragma unroll
    for (int j = 0; j < 4; ++j) {
#pragma unroll
      for (int r = 0; r < 8; ++r) {
        float a = (j == 0) ? av[r].x : (j == 1) ? av[r].y : (j == 2) ? av[r].z : av[r].w;
        acc[r] = fmaf(a, w4[j], acc[r]);
      }
    }
  }

#pragma unroll
  for (int r = 0; r < 8; ++r) {
    int rr = rb0 + wv * 8 + r;
    if (rr < kN) out[(size_t)rr * kH + ooff + lane] = fmaxf(acc[r], 0.0f);
  }
}

inline float* align16(void* p) {
  return (float*)(((uintptr_t)p + 15) & ~(uintptr_t)15);
}

}  // namespace

extern "C" void kernel_launch(void* const* d_in, const int* in_sizes, int n_in,
                              void* d_out, int out_size, void* d_ws, size_t ws_size,
                              hipStream_t stream) {
  const int*   pos     = (const int*)d_in[0];
  const int*   neg     = (const int*)d_in[1];
  const float* users   = (const float*)d_in[2];
  const float* items   = (const float*)d_in[3];
  const float* c1_wpl  = (const float*)d_in[4];
  const float* c1_wpr  = (const float*)d_in[5];
  const float* c1_bpr  = (const float*)d_in[6];
  const float* c1_wnl  = (const float*)d_in[7];
  const float* c1_wnr  = (const float*)d_in[8];
  const float* c1_bnr  = (const float*)d_in[9];
  const float* cw_pl   = (const float*)d_in[10];
  const float* cw_pr   = (const float*)d_in[11];
  const float* cb_pr   = (const float*)d_in[12];
  const float* cw_nl   = (const float*)d_in[13];
  const float* cw_nr   = (const float*)d_in[14];
  const float* cb_nr   = (const float*)d_in[15];
  float* out = (float*)d_out;

  const int* pos_src = pos;
  const int* pos_dst = pos + kEP;
  const int* neg_src = neg;
  const int* neg_dst = neg + kEN;

  // ---- workspace layout ----
  float* invp = (float*)d_ws;
  float* invn = invp + kN;
  int* degp   = (int*)(invn + kN);
  int* degn   = degp + kN;
  int* offp   = degn + kN;
  int* offn   = offp + kN + 1;
  int* sums   = offn + kN + 1;
  int* eidp   = sums + 256;
  int* eidn   = eidp + kEP;
  float* aggP = align16(eidn + kEN);
  float* aggN = aggP + (size_t)kN * kH;
  const size_t need = (size_t)((char*)(aggN + (size_t)kN * kH) - (char*)d_ws);
  if (ws_size < need) return;

  const int nbP = (kN + SCAN_TILE - 1) / SCAN_TILE;

  // ---- degree counts + inverses ----
  hipMemsetAsync(degp, 0, (size_t)2 * kN * sizeof(int), stream);
  count_kernel<<<(kEP + 255) / 256, 256, 0, stream>>>(pos_dst, kEP, degp);
  count_kernel<<<(kEN + 255) / 256, 256, 0, stream>>>(neg_dst, kEN, degn);
  inv_kernel<<<(kN + 255) / 256, 256, 0, stream>>>(degp, invp, kN);
  inv_kernel<<<(kN + 255) / 256, 256, 0, stream>>>(degn, invn, kN);

  // ---- CSR build (pos) ----
  scan_partial<<<nbP, SCAN_BS, 0, stream>>>(degp, kN, offp, sums);
  scan_sums<<<1, SCAN_BS, 0, stream>>>(sums, nbP);
  scan_add<<<(kN + 255) / 256, 256, 0, stream>>>(offp, kN, sums);
  hipMemcpyAsync(degp, offp, (size_t)kN * sizeof(int), hipMemcpyDeviceToDevice, stream);
  fill_kernel<<<(kEP + 255) / 256, 256, 0, stream>>>(pos_src, pos_dst, kEP, degp, eidp);

  // ---- CSR build (neg) ----
  scan_partial<<<nbP, SCAN_BS, 0, stream>>>(degn, kN, offn, sums);
  scan_sums<<<1, SCAN_BS, 0, stream>>>(sums, nbP);
  scan_add<<<(kN + 255) / 256, 256, 0, stream>>>(offn, kN, sums);
  hipMemcpyAsync(degn, offn, (size_t)kN * sizeof(int), hipMemcpyDeviceToDevice, stream);
  fill_kernel<<<(kEN + 255) / 256, 256, 0, stream>>>(neg_src, neg_dst, kEN, degn, eidn);

  const int gA = (kN + 7) / 8;
  const int gG = (kN + 31) / 32;

  // ---- layer 1 ----
  agg_csr<true><<<gA, 256, 0, stream>>>(offp, eidp, invp, users, items, aggP);
  agg_csr<true><<<gA, 256, 0, stream>>>(offn, eidn, invn, users, items, aggN);
  gemm2<128, true><<<gG, 256, 0, stream>>>(aggP, 0, aggP, 64, c1_wpl,
                                           users, items, 0, c1_wpr, c1_bpr, out, 0);
  gemm2<128, true><<<gG, 256, 0, stream>>>(aggN, 0, aggN, 64, c1_wnl,
                                           users, items, 0, c1_wnr, c1_bnr, out, 64);

  // ---- inner layers: z lives in d_out, updated in place ----
  for (int l = 0; l < kL; ++l) {
    const float* wpl = cw_pl + (size_t)l * kH * 64;
    const float* wpr = cw_pr + (size_t)l * 64 * 64;
    const float* bpr = cb_pr + (size_t)l * 64;
    const float* wnl = cw_nl + (size_t)l * kH * 64;
    const float* wnr = cw_nr + (size_t)l * 64 * 64;
    const float* bnr = cb_nr + (size_t)l * 64;

    // aggP = mean_p(z) = [a_pp | a_np]; aggN = mean_n(z) = [a_pn | a_nn]
    agg_csr<false><<<gA, 256, 0, stream>>>(offp, eidp, invp, out, nullptr, aggP);
    agg_csr<false><<<gA, 256, 0, stream>>>(offn, eidn, invn, out, nullptr, aggN);

    // out_pos = relu(concat(a_pp, a_nn) @ wpl + zp @ wpr + bpr)
    gemm2<64, false><<<gG, 256, 0, stream>>>(aggP, 0, aggN, 64, wpl,
                                             out, nullptr, 0, wpr, bpr, out, 0);
    // out_neg = relu(concat(a_np, a_pn) @ wnl + zn @ wnr + bnr)
    gemm2<64, false><<<gG, 256, 0, stream>>>(aggP, 64, aggN, 0, wnl,
                                             out, nullptr, 64, wnr, bnr, out, 64);
  }
}